// Round 2
// baseline (1805.796 us; speedup 1.0000x reference)
//
#include <hip/hip_runtime.h>
#include <hip/hip_bf16.h>
#include <math.h>

typedef unsigned short u16;
typedef __attribute__((ext_vector_type(8))) short short8;
typedef __attribute__((ext_vector_type(4))) float floatx4;

#define B_N 4096
#define P_N 16
#define D_N 512
#define F_N 2048
#define E_N 8
#define TS 2
#define M_ROWS (TS*P_N)      // 32
#define FC 32
#define NCH (F_N/FC)         // 64
#define NPID 64
#define WELEM ((size_t)D_N*F_N)   // 1048576 elems / expert / weight

// ---- workspace layout (bytes) ----
#define CNT_OFF   0                        // 64 int
#define PREF_OFF  256                      // 64 int (tile prefix)
#define SL_OFF    4096                     // 64*4096 int
#define GL_OFF    (SL_OFF + NPID*B_N*4)    // 64*4096 float2
#define W1F_OFF   (GL_OFF + NPID*B_N*8)    // 16 MiB frag-linear W1 (bf16)
#define W2F_OFF   (W1F_OFF + 16777216)     // 16 MiB frag-linear W2 (bf16)
// total ~36.7 MB

__device__ __forceinline__ void gld16(const void* g, void* l) {
  __builtin_amdgcn_global_load_lds(
      (__attribute__((address_space(1))) void*)g,
      (__attribute__((address_space(3))) void*)l, 16, 0, 0);
}

__device__ __forceinline__ short bfq(float x) {
  union { __hip_bfloat16 h; short s; } c; c.h = __float2bfloat16(x); return c.s;
}

// ---------------- router: noisy top-2 + pair bucketing (fp32 in) ----------------
__global__ __launch_bounds__(256) void router_kernel(
    const float* __restrict__ aff, const float* __restrict__ noi,
    int* __restrict__ cnt, int* __restrict__ slist, float2* __restrict__ glist)
{
  int b = blockIdx.x*256 + threadIdx.x;
  if (b >= B_N) return;
  float v0 = -INFINITY, v1 = -INFINITY; int i0 = -1, i1 = -1;
  #pragma unroll
  for (int e = 0; e < E_N; ++e) {
    float a = aff[b*E_N + e];
    float n = noi[b*E_N + e];
    float sp = fmaxf(a, 0.f) + log1pf(expf(-fabsf(a)));   // softplus
    float x = a + n * sp;
    if (x > v0) { v1 = v0; i1 = i0; v0 = x; i0 = e; }
    else if (x > v1) { v1 = x; i1 = e; }
  }
  float g0 = 1.f / (1.f + expf(v1 - v0));   // softmax over the two kept logits
  float g1 = 1.f - g0;
  int emin = min(i0, i1), emax = max(i0, i1);
  float glo = (i0 == emin) ? g0 : g1;
  float ghi = (i0 == emin) ? g1 : g0;
  int pid = emin*E_N + emax;
  int pos = atomicAdd(&cnt[pid], 1);
  slist[pid*B_N + pos] = b;
  glist[pid*B_N + pos] = make_float2(glo, ghi);
}

// ---------------- plan: exclusive prefix of per-pair tile counts ----------------
__global__ void plan_kernel(const int* __restrict__ cnt, int* __restrict__ prefix) {
  int lane = threadIdx.x;            // launched with 64 threads (1 wave)
  int nt = (cnt[lane] + TS - 1) / TS;
  int x = nt;
  #pragma unroll
  for (int off = 1; off < 64; off <<= 1) {
    int y = __shfl_up(x, off);
    if (lane >= off) x += y;
  }
  prefix[lane] = x - nt;             // exclusive scan
}

// ---------------- weight prep: fp32 -> bf16 frag-linear order ----------------
// W1 [E][D][F] fp32 -> per (e,fc): [nt(2)][ks(16)][lane(64)][j(8)] bf16
//   f = fc*32 + nt*16 + (lane&15); d = ks*32 + (lane>>4)*8 + j  (B operand: k=d, n=f)
__global__ __launch_bounds__(256) void prep_w1(const float* __restrict__ W1, u16* __restrict__ W1f) {
  int g = blockIdx.x*256 + threadIdx.x;       // 2^20 granules
  int lane = g & 63;
  int ks = (g >> 6) & 15;
  int nt = (g >> 10) & 1;
  int fc = (g >> 11) & 63;
  int e  = (g >> 17) & 7;
  int f  = fc*32 + nt*16 + (lane & 15);
  int d0 = ks*32 + ((lane >> 4) << 3);
  const float* src = W1 + (size_t)e*WELEM + f;
  short8 v;
  #pragma unroll
  for (int j = 0; j < 8; ++j) v[j] = bfq(src[(size_t)(d0 + j)*F_N]);
  ((short8*)W1f)[g] = v;
}
// W2 [E][F][D] fp32 -> per (e,fc): [nt(32)][lane(64)][j(8)] bf16
//   d = nt*16 + (lane&15); f = fc*32 + (lane>>4)*8 + j  (B operand: k=f, n=d)
__global__ __launch_bounds__(256) void prep_w2(const float* __restrict__ W2, u16* __restrict__ W2f) {
  int g = blockIdx.x*256 + threadIdx.x;
  int lane = g & 63;
  int nt = (g >> 6) & 31;
  int fc = (g >> 11) & 63;
  int e  = (g >> 17) & 7;
  int d  = nt*16 + (lane & 15);
  int f0 = fc*32 + ((lane >> 4) << 3);
  const float* src = W2 + (size_t)e*WELEM + d;
  short8 v;
  #pragma unroll
  for (int j = 0; j < 8; ++j) v[j] = bfq(src[(size_t)(f0 + j)*D_N]);
  ((short8*)W2f)[g] = v;
}

// ---------------- fused MoE MLP: per block = 2 samples x both experts ----------------
__global__ __launch_bounds__(256) void moe_main(
    const float* __restrict__ X,
    const u16* __restrict__ W1f, const u16* __restrict__ W2f,
    const float* __restrict__ b1, const float* __restrict__ b2,
    const int* __restrict__ cnt, const int* __restrict__ prefix,
    const int* __restrict__ slist, const float2* __restrict__ glist,
    float* __restrict__ out)
{
  __shared__ u16 X_lds[M_ROWS][520];   // +8 pad: A-frag reads stay ≤2-way banked
  __shared__ u16 Wbuf[FC*D_N];         // 32 KB, shared by B1/B2 stages
  __shared__ u16 h_lds[M_ROWS][40];    // gated gelu(h) chunk, bf16

  const int tid = threadIdx.x;
  const int lane = tid & 63;
  const int wave = tid >> 6;

  // locate (pid, tile) via ballot over tile-prefix
  int t = blockIdx.x;
  int pf = prefix[lane];
  unsigned long long bal = __ballot(pf <= t);
  int pid = __popcll(bal) - 1;
  int tile = t - __shfl(pf, pid);
  int c = cnt[pid];
  if (tile >= (c + TS - 1)/TS) return;
  int base = tile*TS;
  int nsamp = min(TS, c - base);

  const int e_lo = pid >> 3, e_hi = pid & 7;
  const int s0 = slist[pid*B_N + base];
  const float2 g0v = glist[pid*B_N + base];
  int s1 = s0; float2 g1v = make_float2(0.f, 0.f);
  if (nsamp > 1) { s1 = slist[pid*B_N + base + 1]; g1v = glist[pid*B_N + base + 1]; }

  // stage X: 32 rows x 512 fp32 -> bf16 LDS, 32B per thread-iter, coalesced
  for (int i = tid; i < M_ROWS*64; i += 256) {
    int r = i >> 6, gc = i & 63;
    int smp = (r & 16) ? s1 : s0;
    const float* src = X + (size_t)(smp*P_N + (r & 15))*D_N + gc*8;
    float4 f0 = *(const float4*)(src);
    float4 f1 = *(const float4*)(src + 4);
    short8 v;
    v[0]=bfq(f0.x); v[1]=bfq(f0.y); v[2]=bfq(f0.z); v[3]=bfq(f0.w);
    v[4]=bfq(f1.x); v[5]=bfq(f1.y); v[6]=bfq(f1.z); v[7]=bfq(f1.w);
    *(short8*)&X_lds[r][gc*8] = v;
  }

  floatx4 Yacc[2][8];
  #pragma unroll
  for (int a = 0; a < 2; ++a)
    #pragma unroll
    for (int q = 0; q < 8; ++q) Yacc[a][q] = (floatx4){0.f,0.f,0.f,0.f};

  const int mt1 = wave & 1, nt1 = wave >> 1;   // GEMM1 tile assignment
  const int rA = lane & 15;
  const int cA = (lane >> 4) * 8;

  for (int xp = 0; xp < 2; ++xp) {
    const int e = xp ? e_hi : e_lo;
    const float gm0 = xp ? g0v.y : g0v.x;
    const float gm1 = xp ? g1v.y : g1v.x;
    const u16* w1e = W1f + (size_t)e*WELEM;
    const u16* w2e = W2f + (size_t)e*WELEM;

    for (int fc = 0; fc < NCH; ++fc) {
      __syncthreads();                       // Wbuf free (prev GEMM2 done / X staged)
      {	// stage B1 chunk (32 KB) via global_load_lds, identity layout
        const u16* gsrc = w1e + (size_t)fc*FC*D_N;
        #pragma unroll
        for (int i = 0; i < 8; ++i) {
          int gidx = wave*512 + i*64;        // wave-uniform base granule
          gld16(gsrc + (size_t)(gidx + lane)*8, (u16*)Wbuf + (size_t)gidx*8);
        }
      }
      __builtin_amdgcn_s_waitcnt(0x0f70);    // vmcnt(0)
      __syncthreads();

      // GEMM1: h[32x32] over K=512
      floatx4 acc1 = (floatx4){0.f,0.f,0.f,0.f};
      #pragma unroll
      for (int ks = 0; ks < 16; ++ks) {
        short8 a = *(const short8*)&X_lds[mt1*16 + rA][ks*32 + cA];
        short8 bb = *(const short8*)&Wbuf[((nt1*16 + ks)*64 + lane)*8];
        acc1 = __builtin_amdgcn_mfma_f32_16x16x32_bf16(a, bb, acc1, 0, 0, 0);
      }
      { // bias + tanh-GELU + gate fold, h -> LDS (C-layout -> A-layout handoff)
        float b1v = b1[e*F_N + fc*FC + nt1*16 + rA];
        float gate = mt1 ? gm1 : gm0;
        #pragma unroll
        for (int i = 0; i < 4; ++i) {
          float v = acc1[i] + b1v;
          float u = 0.7978845608028654f * (v + 0.044715f*v*v*v);
          float hq = 0.5f * v * (1.f + tanhf(u)) * gate;
          h_lds[mt1*16 + (lane>>4)*4 + i][nt1*16 + rA] = (u16)bfq(hq);
        }
      }
      __syncthreads();                       // GEMM1 Wbuf reads done + h visible
      { // stage B2 chunk (32 KB) over Wbuf
        const u16* gsrc = w2e + (size_t)fc*FC*D_N;
        #pragma unroll
        for (int i = 0; i < 8; ++i) {
          int gidx = wave*512 + i*64;
          gld16(gsrc + (size_t)(gidx + lane)*8, (u16*)Wbuf + (size_t)gidx*8);
        }
      }
      __builtin_amdgcn_s_waitcnt(0x0f70);
      __syncthreads();

      // GEMM2: Y[32x512] += h[32x32] @ W2chunk[32x512]; wave owns d in [wave*128, +128)
      short8 a0 = *(const short8*)&h_lds[rA][cA];
      short8 a1 = *(const short8*)&h_lds[16 + rA][cA];
      #pragma unroll
      for (int n2 = 0; n2 < 8; ++n2) {
        short8 bb = *(const short8*)&Wbuf[((wave*8 + n2)*64 + lane)*8];
        Yacc[0][n2] = __builtin_amdgcn_mfma_f32_16x16x32_bf16(a0, bb, Yacc[0][n2], 0, 0, 0);
        Yacc[1][n2] = __builtin_amdgcn_mfma_f32_16x16x32_bf16(a1, bb, Yacc[1][n2], 0, 0, 0);
      }
    }
  }

  // epilogue: out[b,p,d] = Y + gate-weighted b2 (fp32 out; C-layout col=lane&15, row=quad*4+i)
  #pragma unroll
  for (int mt = 0; mt < 2; ++mt) {
    if (mt == 1 && nsamp < 2) break;
    int smp = mt ? s1 : s0;
    float2 gv = mt ? g1v : g0v;
    #pragma unroll
    for (int n2 = 0; n2 < 8; ++n2) {
      int dcol = wave*128 + n2*16 + rA;
      float b2v = gv.x * b2[e_lo*D_N + dcol]
                + gv.y * b2[e_hi*D_N + dcol];
      #pragma unroll
      for (int i = 0; i < 4; ++i) {
        int p = (lane >> 4)*4 + i;
        out[(size_t)(smp*P_N + p)*D_N + dcol] = Yacc[mt][n2][i] + b2v;
      }
    }
  }
}

extern "C" void kernel_launch(void* const* d_in, const int* in_sizes, int n_in,
                              void* d_out, int out_size, void* d_ws, size_t ws_size,
                              hipStream_t stream) {
  const float* X   = (const float*)d_in[0];
  // d_in[1] patch_embedding: only defines output shape; values unused
  const float* aff = (const float*)d_in[2];
  const float* noi = (const float*)d_in[3];
  const float* W1  = (const float*)d_in[4];
  const float* b1  = (const float*)d_in[5];
  const float* W2  = (const float*)d_in[6];
  const float* b2  = (const float*)d_in[7];

  char* ws   = (char*)d_ws;
  int* cnt   = (int*)(ws + CNT_OFF);
  int* pref  = (int*)(ws + PREF_OFF);
  int* slist = (int*)(ws + SL_OFF);
  float2* glist = (float2*)(ws + GL_OFF);
  u16* W1f   = (u16*)(ws + W1F_OFF);
  u16* W2f   = (u16*)(ws + W2F_OFF);

  hipMemsetAsync(cnt, 0, NPID*sizeof(int), stream);
  hipLaunchKernelGGL(router_kernel, dim3(B_N/256), dim3(256), 0, stream, aff, noi, cnt, slist, glist);
  hipLaunchKernelGGL(plan_kernel, dim3(1), dim3(64), 0, stream, cnt, pref);
  hipLaunchKernelGGL(prep_w1, dim3(4096), dim3(256), 0, stream, W1, (u16*)W1f);
  hipLaunchKernelGGL(prep_w2, dim3(4096), dim3(256), 0, stream, W2, (u16*)W2f);
  // max total tiles = sum ceil(c_p/2) <= (4096+64)/2 = 2080
  hipLaunchKernelGGL(moe_main, dim3(2080), dim3(256), 0, stream,
                     X, W1f, W2f, b1, b2, cnt, pref, slist, glist, (float*)d_out);
}